// Round 6
// baseline (3189.321 us; speedup 1.0000x reference)
//
#include <hip/hip_runtime.h>
#include <hip/hip_bf16.h>
#include <hip/hip_cooperative_groups.h>
#include <math.h>

namespace cg = cooperative_groups;

#define HID   1024
#define IN_D  600
#define IN_DP 608      // 600 padded to multiple of 32
#define BATCH 2048
#define TSTEP 20
#define BT    (BATCH * TSTEP)   // 40960
#define G3    3072

typedef __attribute__((ext_vector_type(8))) short bf16x8;
typedef __attribute__((ext_vector_type(4))) float f32x4;

#define GLB(p) ((const __attribute__((address_space(1))) void*)(p))
#define LDS(p) ((__attribute__((address_space(3))) void*)(p))

__device__ __forceinline__ short f2bf(float f) {
    __hip_bfloat16 b = __float2bfloat16(f);
    return *(short*)&b;
}
__device__ __forceinline__ float bf2f(short s) {
    __hip_bfloat16 b = *(__hip_bfloat16*)&s;
    return __bfloat162float(b);
}

// ---------------------------------------------------------------------------
// Input projection: gx[m, n] = bf16( x_bf[m, :] . Wih[n, :] + b_ih[n] )
// where m = t*BATCH + b (x_bf pre-transposed to [t][b] row order), so the
// epilogue writes row-major with no div. 128x128 tile, m97 structure.
// ---------------------------------------------------------------------------
__global__ __launch_bounds__(256) void gemm_input(const short* __restrict__ X,
                                                  const short* __restrict__ W,
                                                  const float* __restrict__ b_ih,
                                                  short* __restrict__ gx) {
    __shared__ short sA[128 * 32];
    __shared__ short sB[128 * 32];

    const int id    = blockIdx.x;
    const int xcd   = id & 7;
    const int local = id >> 3;          // 0..959
    const int nsub  = local % 3;
    const int mblk  = local / 3;        // 0..319
    const int m0 = mblk * 128;
    const int n0 = (xcd * 3 + nsub) * 128;

    const int tid  = threadIdx.x;
    const int wave = tid >> 6;
    const int lane = tid & 63;
    const int wm = (wave >> 1) * 64;
    const int wn = (wave & 1) * 64;

    const int srow = tid >> 2;
    const int scol = (tid & 3) * 8;
    const int fm = lane & 15;
    const int fq = lane >> 4;

    f32x4 acc[4][4] = {};

    for (int k0 = 0; k0 < IN_DP; k0 += 32) {
#pragma unroll
        for (int j = 0; j < 2; ++j) {
            const short* ga = X + (size_t)(m0 + j * 64 + srow) * IN_DP + k0 + scol;
            __builtin_amdgcn_global_load_lds(GLB(ga), LDS(sA + j * 2048 + wave * 512), 16, 0, 0);
            const short* gb = W + (size_t)(n0 + j * 64 + srow) * IN_DP + k0 + scol;
            __builtin_amdgcn_global_load_lds(GLB(gb), LDS(sB + j * 2048 + wave * 512), 16, 0, 0);
        }
        __syncthreads();

        bf16x8 af[4], bf[4];
#pragma unroll
        for (int mi = 0; mi < 4; ++mi)
            af[mi] = *(const bf16x8*)(sA + (wm + mi * 16 + fm) * 32 + fq * 8);
#pragma unroll
        for (int ni = 0; ni < 4; ++ni)
            bf[ni] = *(const bf16x8*)(sB + (wn + ni * 16 + fm) * 32 + fq * 8);
#pragma unroll
        for (int mi = 0; mi < 4; ++mi)
#pragma unroll
            for (int ni = 0; ni < 4; ++ni)
                acc[mi][ni] = __builtin_amdgcn_mfma_f32_16x16x32_bf16(af[mi], bf[ni], acc[mi][ni], 0, 0, 0);
        __syncthreads();
    }

    // D frag: row = fq*4 + r, col = fm. gm already equals t*BATCH + b.
#pragma unroll
    for (int ni = 0; ni < 4; ++ni) {
        int gn = n0 + wn + ni * 16 + fm;
        float bias = b_ih[gn];
#pragma unroll
        for (int mi = 0; mi < 4; ++mi) {
#pragma unroll
            for (int r = 0; r < 4; ++r) {
                int gm = m0 + wm + mi * 16 + fq * 4 + r;
                gx[(size_t)gm * G3 + gn] = f2bf(acc[mi][ni][r] + bias);
            }
        }
    }
}

// ---------------------------------------------------------------------------
// Persistent GRU: all 20 steps in ONE cooperative kernel, grid.sync between.
// 256 blocks x 512 threads. Block tile: 128 batch x 64 j x 3 gates.
// Wr is gate-block-interleaved: row jb*48 + g*16 + ji  <-  W_hh[g*1024+jb*16+ji]
// so a block's 192 B-rows are contiguous: [j0*3, j0*3+192).
// 8 waves = 2(m) x 4(j-group of 16). Wave: 4 m-frags x 3 gates, BK=64, dbuf.
// XCD swizzle: xcd=id&7 owns 2 j-blocks (its 786 KB Wr slice stays L2-hot
// across all 20 steps).
// ---------------------------------------------------------------------------
__global__ __launch_bounds__(512) void gru_persist(const short* __restrict__ Wr,
                                                   const short* __restrict__ gx,
                                                   const float* __restrict__ b_hh,
                                                   float* __restrict__ hf,
                                                   short* __restrict__ hb0,
                                                   short* __restrict__ hb1,
                                                   float* __restrict__ out) {
    cg::grid_group grid = cg::this_grid();

    __shared__ short sA[2][128 * 64];   // 2 x 16 KB
    __shared__ short sB[2][192 * 64];   // 2 x 24 KB

    const int id   = blockIdx.x;        // 0..255
    const int xcd  = id & 7;
    const int jsub = (id >> 3) & 1;
    const int mblk = id >> 4;           // 0..15
    const int j0 = (xcd * 2 + jsub) * 64;
    const int m0 = mblk * 128;

    const int tid  = threadIdx.x;
    const int wave = tid >> 6;          // 0..7
    const int lane = tid & 63;
    const int wm   = (wave >> 2) * 64;  // 0 / 64
    const int wg   = wave & 3;          // j-group 0..3
    const int fm   = lane & 15;
    const int fq   = lane >> 4;

    const int srow8 = lane >> 3;        // 0..7
    const int scol  = (lane & 7) * 8;   // shorts

    const int jlane = j0 + wg * 16 + fm;
    const float bh_r = b_hh[jlane];
    const float bh_i = b_hh[HID + jlane];
    const float bh_n = b_hh[2 * HID + jlane];
    const short* Wblk = Wr + (size_t)(j0 * 3) * HID;

    for (int t = 0; t < TSTEP; ++t) {
        const short* hin = (t & 1) ? hb1 : hb0;
        short* hout      = (t & 1) ? hb0 : hb1;

        f32x4 acc[4][3] = {};   // [m-frag][gate]

        auto stage = [&](int kc, int bsel) {
            int k0 = kc * 64;
#pragma unroll
            for (int jj = 0; jj < 2; ++jj) {
                int row = jj * 64 + wave * 8;
                const short* g = hin + (size_t)(m0 + row + srow8) * HID + k0 + scol;
                __builtin_amdgcn_global_load_lds(GLB(g), LDS(&sA[bsel][row * 64]), 16, 0, 0);
            }
#pragma unroll
            for (int jj = 0; jj < 3; ++jj) {
                int row = jj * 64 + wave * 8;
                const short* g = Wblk + (size_t)(row + srow8) * HID + k0 + scol;
                __builtin_amdgcn_global_load_lds(GLB(g), LDS(&sB[bsel][row * 64]), 16, 0, 0);
            }
        };

        stage(0, 0);
        for (int ic = 0; ic < 16; ++ic) {
            int cur = ic & 1;
            __syncthreads();                    // drains staging for buf cur
            if (ic + 1 < 16) stage(ic + 1, cur ^ 1);

            bf16x8 af[4][2], bg[3][2];
#pragma unroll
            for (int mi = 0; mi < 4; ++mi)
#pragma unroll
                for (int kq = 0; kq < 2; ++kq)
                    af[mi][kq] = *(const bf16x8*)(&sA[cur][(wm + mi * 16 + fm) * 64 + kq * 32 + fq * 8]);
#pragma unroll
            for (int g = 0; g < 3; ++g)
#pragma unroll
                for (int kq = 0; kq < 2; ++kq)
                    bg[g][kq] = *(const bf16x8*)(&sB[cur][(wg * 48 + g * 16 + fm) * 64 + kq * 32 + fq * 8]);
#pragma unroll
            for (int mi = 0; mi < 4; ++mi)
#pragma unroll
                for (int g = 0; g < 3; ++g)
#pragma unroll
                    for (int kq = 0; kq < 2; ++kq)
                        acc[mi][g] = __builtin_amdgcn_mfma_f32_16x16x32_bf16(af[mi][kq], bg[g][kq], acc[mi][g], 0, 0, 0);
        }

        // Epilogue: D frag row = fq*4 + r, col = fm (= jlane).
        const short* gxt = gx + (size_t)t * BATCH * G3;
#pragma unroll
        for (int mi = 0; mi < 4; ++mi) {
#pragma unroll
            for (int r = 0; r < 4; ++r) {
                int gm = m0 + wm + mi * 16 + fq * 4 + r;
                const short* gr = gxt + (size_t)gm * G3;
                float xr = bf2f(gr[jlane]);
                float xi = bf2f(gr[HID + jlane]);
                float xn = bf2f(gr[2 * HID + jlane]);

                float rg = 1.0f / (1.0f + __expf(-(xr + acc[mi][0][r] + bh_r)));
                float ig = 1.0f / (1.0f + __expf(-(xi + acc[mi][1][r] + bh_i)));
                float ng = tanhf(xn + rg * (acc[mi][2][r] + bh_n));

                size_t idx = (size_t)gm * HID + jlane;
                float h  = hf[idx];
                float hy = ng + ig * (h - ng);
                hf[idx] = hy;
                hout[idx] = f2bf(hy);
                if (t == TSTEP - 1) out[idx] = hy;
            }
        }
        __threadfence();   // make h stores visible device-wide (cross-XCD)
        grid.sync();
    }
}

// x [b][t][600] fp32 -> x_bf [t*B + b][608] bf16 zero-padded (transpose)
__global__ __launch_bounds__(256) void cvt_x(const float* __restrict__ X, short* __restrict__ Xb) {
    int rd = blockIdx.x;             // dst row = t*BATCH + b
    int tt = rd >> 11;               // /2048
    int b  = rd & (BATCH - 1);
    const float* s = X + ((size_t)b * TSTEP + tt) * IN_D;
    short* d = Xb + (size_t)rd * IN_DP;
    for (int c = threadIdx.x; c < IN_DP; c += 256)
        d[c] = (c < IN_D) ? f2bf(s[c]) : (short)0;
}

// W_ih [3072,600] fp32 -> [3072,608] bf16 zero-padded
__global__ __launch_bounds__(256) void cvt_wih(const float* __restrict__ W, short* __restrict__ Wb) {
    int r = blockIdx.x;
    for (int c = threadIdx.x; c < IN_DP; c += 256) {
        float v = (c < IN_D) ? W[(size_t)r * IN_D + c] : 0.f;
        Wb[(size_t)r * IN_DP + c] = f2bf(v);
    }
}

// W_hh -> Wr gate-block-interleaved bf16: Wr[jb*48+g*16+ji] = Whh[g*1024+jb*16+ji]
__global__ __launch_bounds__(256) void cvt_whh(const float* __restrict__ W, short* __restrict__ Wr) {
    int n  = blockIdx.x;             // dst row 0..3071
    int jb = n / 48;
    int rem = n - jb * 48;
    int g  = rem >> 4;
    int ji = rem & 15;
    const float* s = W + (size_t)(g * HID + jb * 16 + ji) * HID;
    short* d = Wr + (size_t)n * HID;
    for (int c = threadIdx.x; c < HID; c += 256) d[c] = f2bf(s[c]);
}

extern "C" void kernel_launch(void* const* d_in, const int* in_sizes, int n_in,
                              void* d_out, int out_size, void* d_ws, size_t ws_size,
                              hipStream_t stream) {
    const float* x    = (const float*)d_in[0];  // [B, T, IN_D]
    const float* W_ih = (const float*)d_in[1];  // [3H, IN_D]
    const float* b_ih = (const float*)d_in[2];
    const float* W_hh = (const float*)d_in[3];  // [3H, HID]
    const float* b_hh = (const float*)d_in[4];
    float* out = (float*)d_out;                 // [B, HID]

    char* p = (char*)d_ws;
    short* gx     = (short*)p;  p += (size_t)BT * G3 * 2;       // 251.7 MB, [t][b][3H]
    short* x_bf   = (short*)p;  p += (size_t)BT * IN_DP * 2;    //  49.8 MB, [t][b][608]
    float* hf     = (float*)p;  p += (size_t)BATCH * HID * 4;   //   8.4 MB
    short* hb0    = (short*)p;  p += (size_t)BATCH * HID * 2;   //   4.2 MB
    short* hb1    = (short*)p;  p += (size_t)BATCH * HID * 2;   //   4.2 MB
    short* Wih_bf = (short*)p;  p += (size_t)G3 * IN_DP * 2;    //   3.7 MB
    short* Whh_r  = (short*)p;  p += (size_t)G3 * HID * 2;      //   6.3 MB
    // total ~328 MB

    cvt_wih<<<G3, 256, 0, stream>>>(W_ih, Wih_bf);
    cvt_whh<<<G3, 256, 0, stream>>>(W_hh, Whh_r);
    cvt_x<<<BT, 256, 0, stream>>>(x, x_bf);
    hipMemsetAsync(hf, 0, (size_t)BATCH * HID * 4, stream);
    hipMemsetAsync(hb0, 0, (size_t)BATCH * HID * 2, stream);

    // One big input projection over all timesteps (M = 40960, 1D swizzled)
    gemm_input<<<7680, 256, 0, stream>>>(x_bf, Wih_bf, b_ih, gx);

    // All 20 recurrent steps in one cooperative persistent kernel
    void* args[] = { (void*)&Whh_r, (void*)&gx, (void*)&b_hh, (void*)&hf,
                     (void*)&hb0, (void*)&hb1, (void*)&out };
    hipLaunchCooperativeKernel((const void*)gru_persist, dim3(256), dim3(512),
                               args, 0, stream);
}

// Round 7
// 1223.338 us; speedup vs baseline: 2.6071x; 2.6071x over previous
//
#include <hip/hip_runtime.h>
#include <hip/hip_bf16.h>
#include <math.h>

#define HID   1024
#define IN_D  600
#define IN_DP 608      // 600 padded to multiple of 32
#define BATCH 2048
#define TSTEP 20
#define BT    (BATCH * TSTEP)   // 40960
#define G3    3072

typedef __attribute__((ext_vector_type(8))) short bf16x8;
typedef __attribute__((ext_vector_type(4))) float f32x4;

#define GLB(p) ((const __attribute__((address_space(1))) void*)(p))
#define LDS(p) ((__attribute__((address_space(3))) void*)(p))

__device__ __forceinline__ short f2bf(float f) {
    __hip_bfloat16 b = __float2bfloat16(f);
    return *(short*)&b;
}
__device__ __forceinline__ float bf2f(short s) {
    __hip_bfloat16 b = *(__hip_bfloat16*)&s;
    return __bfloat162float(b);
}

// ---------------------------------------------------------------------------
// Input projection: gx[m, n] = bf16( x_bf[m, :] . Wih[n, :] + b_ih[n] ),
// m = t*BATCH + b (x_bf pre-transposed), row-major epilogue, m97 structure.
// ---------------------------------------------------------------------------
__global__ __launch_bounds__(256) void gemm_input(const short* __restrict__ X,
                                                  const short* __restrict__ W,
                                                  const float* __restrict__ b_ih,
                                                  short* __restrict__ gx) {
    __shared__ short sA[128 * 32];
    __shared__ short sB[128 * 32];

    const int id    = blockIdx.x;
    const int xcd   = id & 7;
    const int local = id >> 3;          // 0..959
    const int nsub  = local % 3;
    const int mblk  = local / 3;        // 0..319
    const int m0 = mblk * 128;
    const int n0 = (xcd * 3 + nsub) * 128;

    const int tid  = threadIdx.x;
    const int wave = tid >> 6;
    const int lane = tid & 63;
    const int wm = (wave >> 1) * 64;
    const int wn = (wave & 1) * 64;

    const int srow = tid >> 2;
    const int scol = (tid & 3) * 8;
    const int fm = lane & 15;
    const int fq = lane >> 4;

    f32x4 acc[4][4] = {};

    for (int k0 = 0; k0 < IN_DP; k0 += 32) {
#pragma unroll
        for (int j = 0; j < 2; ++j) {
            const short* ga = X + (size_t)(m0 + j * 64 + srow) * IN_DP + k0 + scol;
            __builtin_amdgcn_global_load_lds(GLB(ga), LDS(sA + j * 2048 + wave * 512), 16, 0, 0);
            const short* gb = W + (size_t)(n0 + j * 64 + srow) * IN_DP + k0 + scol;
            __builtin_amdgcn_global_load_lds(GLB(gb), LDS(sB + j * 2048 + wave * 512), 16, 0, 0);
        }
        __syncthreads();

        bf16x8 af[4], bf[4];
#pragma unroll
        for (int mi = 0; mi < 4; ++mi)
            af[mi] = *(const bf16x8*)(sA + (wm + mi * 16 + fm) * 32 + fq * 8);
#pragma unroll
        for (int ni = 0; ni < 4; ++ni)
            bf[ni] = *(const bf16x8*)(sB + (wn + ni * 16 + fm) * 32 + fq * 8);
#pragma unroll
        for (int mi = 0; mi < 4; ++mi)
#pragma unroll
            for (int ni = 0; ni < 4; ++ni)
                acc[mi][ni] = __builtin_amdgcn_mfma_f32_16x16x32_bf16(af[mi], bf[ni], acc[mi][ni], 0, 0, 0);
        __syncthreads();
    }

#pragma unroll
    for (int ni = 0; ni < 4; ++ni) {
        int gn = n0 + wn + ni * 16 + fm;
        float bias = b_ih[gn];
#pragma unroll
        for (int mi = 0; mi < 4; ++mi) {
#pragma unroll
            for (int r = 0; r < 4; ++r) {
                int gm = m0 + wm + mi * 16 + fq * 4 + r;
                gx[(size_t)gm * G3 + gn] = f2bf(acc[mi][ni][r] + bias);
            }
        }
    }
}

// ---------------------------------------------------------------------------
// Fused recurrent step v3: 128(batch) x 32(j) x 3 gates per block.
// Wr gate-interleaved (row jb*48+g*16+ji), so block B-rows = [j0*3, j0*3+96).
// BK=32 (64 B LDS rows -> conflict-free, the R4/R5 BK=64 layout was 8-16-way
// bank-conflicted), double-buffered, 32 k-chunks. 256 thr = 4 waves:
// wave = (m-half wave>>1) x (j-group wave&1); per wave 4 m-frags x 3 gates.
// Grid 512 = 2 blocks/CU. XCD swizzle: xcd owns 4 j-blocks (Wr slice L2-hot).
// ---------------------------------------------------------------------------
__global__ __launch_bounds__(256) void gru_step(const short* __restrict__ hb_in,
                                                const short* __restrict__ Wr,
                                                const short* __restrict__ gx,
                                                const float* __restrict__ b_hh,
                                                float* __restrict__ hf,
                                                short* __restrict__ hb_out,
                                                float* __restrict__ out,
                                                int t, int last) {
    __shared__ short sA[2][128 * 32];   // 2 x 8 KB
    __shared__ short sB[2][96 * 32];    // 2 x 6 KB

    const int id   = blockIdx.x;
    const int xcd  = id & 7;
    const int jsub = (id >> 3) & 3;
    const int mblk = id >> 5;           // 0..15
    const int j0 = (xcd * 4 + jsub) * 32;
    const int m0 = mblk * 128;

    const int tid  = threadIdx.x;
    const int wave = tid >> 6;
    const int lane = tid & 63;
    const int wm = (wave >> 1) * 64;
    const int jg = wave & 1;
    const int fm = lane & 15;
    const int fq = lane >> 4;

    const int srow = lane >> 2;         // 0..15
    const int scol = (lane & 3) * 8;

    const short* Wblk = Wr + (size_t)(j0 * 3) * HID;   // 96 rows, K=1024

    f32x4 acc[4][3] = {};   // [m-frag][gate]

    auto stage = [&](int kc, int bsel) {
        int k0 = kc * 32;
#pragma unroll
        for (int jj = 0; jj < 2; ++jj) {
            int row = wave * 32 + jj * 16;
            const short* g = hb_in + (size_t)(m0 + row + srow) * HID + k0 + scol;
            __builtin_amdgcn_global_load_lds(GLB(g), LDS(&sA[bsel][row * 32]), 16, 0, 0);
        }
        if (wave < 3) {
#pragma unroll
            for (int jj = 0; jj < 2; ++jj) {
                int row = wave * 32 + jj * 16;
                const short* g = Wblk + (size_t)(row + srow) * HID + k0 + scol;
                __builtin_amdgcn_global_load_lds(GLB(g), LDS(&sB[bsel][row * 32]), 16, 0, 0);
            }
        }
    };

    stage(0, 0);
    for (int ic = 0; ic < 32; ++ic) {
        int cur = ic & 1;
        __syncthreads();                 // drains staging for buf cur
        if (ic + 1 < 32) stage(ic + 1, cur ^ 1);

        bf16x8 af[4], bg[3];
#pragma unroll
        for (int mi = 0; mi < 4; ++mi)
            af[mi] = *(const bf16x8*)(&sA[cur][(wm + mi * 16 + fm) * 32 + fq * 8]);
#pragma unroll
        for (int g = 0; g < 3; ++g)
            bg[g] = *(const bf16x8*)(&sB[cur][(jg * 48 + g * 16 + fm) * 32 + fq * 8]);
#pragma unroll
        for (int mi = 0; mi < 4; ++mi)
#pragma unroll
            for (int g = 0; g < 3; ++g)
                acc[mi][g] = __builtin_amdgcn_mfma_f32_16x16x32_bf16(af[mi], bg[g], acc[mi][g], 0, 0, 0);
    }

    // Epilogue. D frag: row = fq*4 + r, col = fm (j = jlane).
    const int jlane = j0 + jg * 16 + fm;
    const float bh_r = b_hh[jlane];
    const float bh_i = b_hh[HID + jlane];
    const float bh_n = b_hh[2 * HID + jlane];
    const short* gxt = gx + (size_t)t * BATCH * G3;

#pragma unroll
    for (int mi = 0; mi < 4; ++mi) {
#pragma unroll
        for (int r = 0; r < 4; ++r) {
            int gm = m0 + wm + mi * 16 + fq * 4 + r;
            const short* gr = gxt + (size_t)gm * G3;
            float xr = bf2f(gr[jlane]);
            float xi = bf2f(gr[HID + jlane]);
            float xn = bf2f(gr[2 * HID + jlane]);

            float rg = 1.0f / (1.0f + __expf(-(xr + acc[mi][0][r] + bh_r)));
            float ig = 1.0f / (1.0f + __expf(-(xi + acc[mi][1][r] + bh_i)));
            float ng = tanhf(xn + rg * (acc[mi][2][r] + bh_n));

            size_t idx = (size_t)gm * HID + jlane;
            float h  = hf[idx];
            float hy = ng + ig * (h - ng);
            hf[idx] = hy;
            hb_out[idx] = f2bf(hy);
            if (last) out[idx] = hy;
        }
    }
}

// x [b][t][600] fp32 -> x_bf [t*B + b][608] bf16 zero-padded (transpose)
__global__ __launch_bounds__(256) void cvt_x(const float* __restrict__ X, short* __restrict__ Xb) {
    int rd = blockIdx.x;             // dst row = t*BATCH + b
    int tt = rd >> 11;               // /2048
    int b  = rd & (BATCH - 1);
    const float* s = X + ((size_t)b * TSTEP + tt) * IN_D;
    short* d = Xb + (size_t)rd * IN_DP;
    for (int c = threadIdx.x; c < IN_DP; c += 256)
        d[c] = (c < IN_D) ? f2bf(s[c]) : (short)0;
}

// W_ih [3072,600] fp32 -> [3072,608] bf16 zero-padded
__global__ __launch_bounds__(256) void cvt_wih(const float* __restrict__ W, short* __restrict__ Wb) {
    int r = blockIdx.x;
    for (int c = threadIdx.x; c < IN_DP; c += 256) {
        float v = (c < IN_D) ? W[(size_t)r * IN_D + c] : 0.f;
        Wb[(size_t)r * IN_DP + c] = f2bf(v);
    }
}

// W_hh -> Wr gate-block-interleaved bf16: Wr[jb*48+g*16+ji] = Whh[g*1024+jb*16+ji]
__global__ __launch_bounds__(256) void cvt_whh(const float* __restrict__ W, short* __restrict__ Wr) {
    int n  = blockIdx.x;             // dst row 0..3071
    int jb = n / 48;
    int rem = n - jb * 48;
    int g  = rem >> 4;
    int ji = rem & 15;
    const float* s = W + (size_t)(g * HID + jb * 16 + ji) * HID;
    short* d = Wr + (size_t)n * HID;
    for (int c = threadIdx.x; c < HID; c += 256) d[c] = f2bf(s[c]);
}

extern "C" void kernel_launch(void* const* d_in, const int* in_sizes, int n_in,
                              void* d_out, int out_size, void* d_ws, size_t ws_size,
                              hipStream_t stream) {
    const float* x    = (const float*)d_in[0];  // [B, T, IN_D]
    const float* W_ih = (const float*)d_in[1];  // [3H, IN_D]
    const float* b_ih = (const float*)d_in[2];
    const float* W_hh = (const float*)d_in[3];  // [3H, HID]
    const float* b_hh = (const float*)d_in[4];
    float* out = (float*)d_out;                 // [B, HID]

    char* p = (char*)d_ws;
    short* gx     = (short*)p;  p += (size_t)BT * G3 * 2;       // 251.7 MB, [t][b][3H]
    short* x_bf   = (short*)p;  p += (size_t)BT * IN_DP * 2;    //  49.8 MB, [t][b][608]
    float* hf     = (float*)p;  p += (size_t)BATCH * HID * 4;   //   8.4 MB
    short* hb0    = (short*)p;  p += (size_t)BATCH * HID * 2;   //   4.2 MB
    short* hb1    = (short*)p;  p += (size_t)BATCH * HID * 2;   //   4.2 MB
    short* Wih_bf = (short*)p;  p += (size_t)G3 * IN_DP * 2;    //   3.7 MB
    short* Whh_r  = (short*)p;  p += (size_t)G3 * HID * 2;      //   6.3 MB
    // total ~328 MB

    cvt_wih<<<G3, 256, 0, stream>>>(W_ih, Wih_bf);
    cvt_whh<<<G3, 256, 0, stream>>>(W_hh, Whh_r);
    cvt_x<<<BT, 256, 0, stream>>>(x, x_bf);
    hipMemsetAsync(hf, 0, (size_t)BATCH * HID * 4, stream);
    hipMemsetAsync(hb0, 0, (size_t)BATCH * HID * 2, stream);

    // One big input projection over all timesteps (M = 40960, 1D swizzled)
    gemm_input<<<7680, 256, 0, stream>>>(x_bf, Wih_bf, b_ih, gx);

    // 20 fused recurrent steps (512 blocks each, XCD-swizzled)
    for (int t = 0; t < TSTEP; ++t) {
        const short* hin = (t & 1) ? hb1 : hb0;
        short* hout      = (t & 1) ? hb0 : hb1;
        gru_step<<<512, 256, 0, stream>>>(hin, Whh_r, gx, b_hh,
                                          hf, hout, out, t, t == TSTEP - 1 ? 1 : 0);
    }
}

// Round 8
// 984.864 us; speedup vs baseline: 3.2383x; 1.2421x over previous
//
#include <hip/hip_runtime.h>
#include <hip/hip_bf16.h>
#include <math.h>

#define HID   1024
#define IN_D  600
#define IN_DP 608      // 600 padded to multiple of 32
#define BATCH 2048
#define TSTEP 20
#define BT    (BATCH * TSTEP)   // 40960
#define G3    3072

typedef __attribute__((ext_vector_type(8))) short bf16x8;
typedef __attribute__((ext_vector_type(4))) float f32x4;

#define GLB(p) ((const __attribute__((address_space(1))) void*)(p))
#define LDS(p) ((__attribute__((address_space(3))) void*)(p))

__device__ __forceinline__ short f2bf(float f) {
    __hip_bfloat16 b = __float2bfloat16(f);
    return *(short*)&b;
}
__device__ __forceinline__ float bf2f(short s) {
    __hip_bfloat16 b = *(__hip_bfloat16*)&s;
    return __bfloat162float(b);
}

// ---------------------------------------------------------------------------
// Input projection: gx[m, n] = bf16( x_bf[m, :] . Wih[n, :] + b_ih[n] ),
// m = t*BATCH + b (x_bf pre-transposed), row-major epilogue, m97 structure.
// ---------------------------------------------------------------------------
__global__ __launch_bounds__(256) void gemm_input(const short* __restrict__ X,
                                                  const short* __restrict__ W,
                                                  const float* __restrict__ b_ih,
                                                  short* __restrict__ gx) {
    __shared__ short sA[128 * 32];
    __shared__ short sB[128 * 32];

    const int id    = blockIdx.x;
    const int xcd   = id & 7;
    const int local = id >> 3;          // 0..959
    const int nsub  = local % 3;
    const int mblk  = local / 3;        // 0..319
    const int m0 = mblk * 128;
    const int n0 = (xcd * 3 + nsub) * 128;

    const int tid  = threadIdx.x;
    const int wave = tid >> 6;
    const int lane = tid & 63;
    const int wm = (wave >> 1) * 64;
    const int wn = (wave & 1) * 64;

    const int srow = tid >> 2;
    const int scol = (tid & 3) * 8;
    const int fm = lane & 15;
    const int fq = lane >> 4;

    f32x4 acc[4][4] = {};

    for (int k0 = 0; k0 < IN_DP; k0 += 32) {
#pragma unroll
        for (int j = 0; j < 2; ++j) {
            const short* ga = X + (size_t)(m0 + j * 64 + srow) * IN_DP + k0 + scol;
            __builtin_amdgcn_global_load_lds(GLB(ga), LDS(sA + j * 2048 + wave * 512), 16, 0, 0);
            const short* gb = W + (size_t)(n0 + j * 64 + srow) * IN_DP + k0 + scol;
            __builtin_amdgcn_global_load_lds(GLB(gb), LDS(sB + j * 2048 + wave * 512), 16, 0, 0);
        }
        __syncthreads();

        bf16x8 af[4], bf[4];
#pragma unroll
        for (int mi = 0; mi < 4; ++mi)
            af[mi] = *(const bf16x8*)(sA + (wm + mi * 16 + fm) * 32 + fq * 8);
#pragma unroll
        for (int ni = 0; ni < 4; ++ni)
            bf[ni] = *(const bf16x8*)(sB + (wn + ni * 16 + fm) * 32 + fq * 8);
#pragma unroll
        for (int mi = 0; mi < 4; ++mi)
#pragma unroll
            for (int ni = 0; ni < 4; ++ni)
                acc[mi][ni] = __builtin_amdgcn_mfma_f32_16x16x32_bf16(af[mi], bf[ni], acc[mi][ni], 0, 0, 0);
        __syncthreads();
    }

#pragma unroll
    for (int ni = 0; ni < 4; ++ni) {
        int gn = n0 + wn + ni * 16 + fm;
        float bias = b_ih[gn];
#pragma unroll
        for (int mi = 0; mi < 4; ++mi) {
#pragma unroll
            for (int r = 0; r < 4; ++r) {
                int gm = m0 + wm + mi * 16 + fq * 4 + r;
                gx[(size_t)gm * G3 + gn] = f2bf(acc[mi][ni][r] + bias);
            }
        }
    }
}

// ---------------------------------------------------------------------------
// Fused recurrent step v4: 128(batch) x 32(j) x 3 gates per block, BK=32,
// double-buffered (conflict-free 64 B LDS rows). Epilogue is global-read-free:
//  - gx tile (3 gates x 128 x 32 = 24 KB) prefetched into LDS at kernel start
//    (in flight behind stage(0); drained by the first barrier)
//  - h[m-tile][j-tile] captured from sA when the K-loop passes chunk j0>>5
//  - h state is bf16-only (no fp32 carrier) -> epilogue only STORES 2 B/elem
// Grid 512, XCD swizzle (xcd owns 4 j-blocks; its Wr slice stays L2-hot).
// ---------------------------------------------------------------------------
__global__ __launch_bounds__(256) void gru_step(const short* __restrict__ hb_in,
                                                const short* __restrict__ Wr,
                                                const short* __restrict__ gx,
                                                const float* __restrict__ b_hh,
                                                short* __restrict__ hb_out,
                                                float* __restrict__ out,
                                                int t, int last) {
    __shared__ short sA[2][128 * 32];   // 2 x 8 KB   h k-chunks
    __shared__ short sB[2][96 * 32];    // 2 x 6 KB   W k-chunks (gate-interleaved)
    __shared__ short sGX[3 * 128 * 32]; // 24 KB      [gate][m][32 j]

    const int id   = blockIdx.x;
    const int xcd  = id & 7;
    const int jsub = (id >> 3) & 3;
    const int mblk = id >> 5;           // 0..15
    const int j0 = (xcd * 4 + jsub) * 32;
    const int m0 = mblk * 128;
    const int hchunk = j0 >> 5;         // k-chunk holding h[:, j0..j0+31]

    const int tid  = threadIdx.x;
    const int wave = tid >> 6;
    const int lane = tid & 63;
    const int wm = (wave >> 1) * 64;
    const int jg = wave & 1;
    const int fm = lane & 15;
    const int fq = lane >> 4;

    const int srow = lane >> 2;         // 0..15
    const int scol = (lane & 3) * 8;

    const short* Wblk = Wr + (size_t)(j0 * 3) * HID;   // 96 rows, K=1024
    const short* gxt  = gx + (size_t)t * BATCH * G3;

    // ---- prefetch gx tile into sGX (6 x 16B per thread, fire-and-forget) ----
    // flat q = it*256 + tid; dest short-offset q*8 = g*4096 + row*32 + (q&3)*8
#pragma unroll
    for (int it = 0; it < 6; ++it) {
        int q = it * 256 + tid;
        int g    = q >> 9;
        int rowq = (q & 511) >> 2;
        int cq   = (q & 3) * 8;
        const short* src = gxt + (size_t)(m0 + rowq) * G3 + g * HID + j0 + cq;
        __builtin_amdgcn_global_load_lds(GLB(src), LDS(sGX + it * 2048 + wave * 512), 16, 0, 0);
    }

    f32x4 acc[4][3] = {};    // [m-frag][gate]
    short hsnap[4][4];       // h[m-frag rows][this lane's j]

    auto stage = [&](int kc, int bsel) {
        int k0 = kc * 32;
#pragma unroll
        for (int jj = 0; jj < 2; ++jj) {
            int row = wave * 32 + jj * 16;
            const short* g = hb_in + (size_t)(m0 + row + srow) * HID + k0 + scol;
            __builtin_amdgcn_global_load_lds(GLB(g), LDS(&sA[bsel][row * 32]), 16, 0, 0);
        }
        if (wave < 3) {
#pragma unroll
            for (int jj = 0; jj < 2; ++jj) {
                int row = wave * 32 + jj * 16;
                const short* g = Wblk + (size_t)(row + srow) * HID + k0 + scol;
                __builtin_amdgcn_global_load_lds(GLB(g), LDS(&sB[bsel][row * 32]), 16, 0, 0);
            }
        }
    };

    const int jj = jg * 16 + fm;        // block-local j (0..31)

    stage(0, 0);
    for (int ic = 0; ic < 32; ++ic) {
        int cur = ic & 1;
        __syncthreads();                 // drains staging for buf cur (+ sGX on ic=0)
        if (ic + 1 < 32) stage(ic + 1, cur ^ 1);

        if (ic == hchunk) {              // snapshot h[:, j0..j0+31] from sA
#pragma unroll
            for (int mi = 0; mi < 4; ++mi)
#pragma unroll
                for (int r = 0; r < 4; ++r)
                    hsnap[mi][r] = sA[cur][(wm + mi * 16 + fq * 4 + r) * 32 + jj];
        }

        bf16x8 af[4], bg[3];
#pragma unroll
        for (int mi = 0; mi < 4; ++mi)
            af[mi] = *(const bf16x8*)(&sA[cur][(wm + mi * 16 + fm) * 32 + fq * 8]);
#pragma unroll
        for (int g = 0; g < 3; ++g)
            bg[g] = *(const bf16x8*)(&sB[cur][(jg * 48 + g * 16 + fm) * 32 + fq * 8]);
#pragma unroll
        for (int mi = 0; mi < 4; ++mi)
#pragma unroll
            for (int g = 0; g < 3; ++g)
                acc[mi][g] = __builtin_amdgcn_mfma_f32_16x16x32_bf16(af[mi], bg[g], acc[mi][g], 0, 0, 0);
    }

    // Epilogue: LDS/register-only inputs; global STORES only.
    const int jlane = j0 + jj;
    const float bh_r = b_hh[jlane];
    const float bh_i = b_hh[HID + jlane];
    const float bh_n = b_hh[2 * HID + jlane];

#pragma unroll
    for (int mi = 0; mi < 4; ++mi) {
#pragma unroll
        for (int r = 0; r < 4; ++r) {
            int mloc = wm + mi * 16 + fq * 4 + r;
            int gm = m0 + mloc;
            float xr = bf2f(sGX[mloc * 32 + jj]);
            float xi = bf2f(sGX[4096 + mloc * 32 + jj]);
            float xn = bf2f(sGX[8192 + mloc * 32 + jj]);

            float rg = 1.0f / (1.0f + __expf(-(xr + acc[mi][0][r] + bh_r)));
            float ig = 1.0f / (1.0f + __expf(-(xi + acc[mi][1][r] + bh_i)));
            float ng = tanhf(xn + rg * (acc[mi][2][r] + bh_n));

            float h  = bf2f(hsnap[mi][r]);
            float hy = ng + ig * (h - ng);
            size_t idx = (size_t)gm * HID + jlane;
            hb_out[idx] = f2bf(hy);
            if (last) out[idx] = hy;
        }
    }
}

// x [b][t][600] fp32 -> x_bf [t*B + b][608] bf16 zero-padded (transpose)
__global__ __launch_bounds__(256) void cvt_x(const float* __restrict__ X, short* __restrict__ Xb) {
    int rd = blockIdx.x;             // dst row = t*BATCH + b
    int tt = rd >> 11;               // /2048
    int b  = rd & (BATCH - 1);
    const float* s = X + ((size_t)b * TSTEP + tt) * IN_D;
    short* d = Xb + (size_t)rd * IN_DP;
    for (int c = threadIdx.x; c < IN_DP; c += 256)
        d[c] = (c < IN_D) ? f2bf(s[c]) : (short)0;
}

// W_ih [3072,600] fp32 -> [3072,608] bf16 zero-padded
__global__ __launch_bounds__(256) void cvt_wih(const float* __restrict__ W, short* __restrict__ Wb) {
    int r = blockIdx.x;
    for (int c = threadIdx.x; c < IN_DP; c += 256) {
        float v = (c < IN_D) ? W[(size_t)r * IN_D + c] : 0.f;
        Wb[(size_t)r * IN_DP + c] = f2bf(v);
    }
}

// W_hh -> Wr gate-block-interleaved bf16: Wr[jb*48+g*16+ji] = Whh[g*1024+jb*16+ji]
__global__ __launch_bounds__(256) void cvt_whh(const float* __restrict__ W, short* __restrict__ Wr) {
    int n  = blockIdx.x;             // dst row 0..3071
    int jb = n / 48;
    int rem = n - jb * 48;
    int g  = rem >> 4;
    int ji = rem & 15;
    const float* s = W + (size_t)(g * HID + jb * 16 + ji) * HID;
    short* d = Wr + (size_t)n * HID;
    for (int c = threadIdx.x; c < HID; c += 256) d[c] = f2bf(s[c]);
}

extern "C" void kernel_launch(void* const* d_in, const int* in_sizes, int n_in,
                              void* d_out, int out_size, void* d_ws, size_t ws_size,
                              hipStream_t stream) {
    const float* x    = (const float*)d_in[0];  // [B, T, IN_D]
    const float* W_ih = (const float*)d_in[1];  // [3H, IN_D]
    const float* b_ih = (const float*)d_in[2];
    const float* W_hh = (const float*)d_in[3];  // [3H, HID]
    const float* b_hh = (const float*)d_in[4];
    float* out = (float*)d_out;                 // [B, HID]

    char* p = (char*)d_ws;
    short* gx     = (short*)p;  p += (size_t)BT * G3 * 2;       // 251.7 MB, [t][b][3H]
    short* x_bf   = (short*)p;  p += (size_t)BT * IN_DP * 2;    //  49.8 MB, [t][b][608]
    short* hb0    = (short*)p;  p += (size_t)BATCH * HID * 2;   //   4.2 MB
    short* hb1    = (short*)p;  p += (size_t)BATCH * HID * 2;   //   4.2 MB
    short* Wih_bf = (short*)p;  p += (size_t)G3 * IN_DP * 2;    //   3.7 MB
    short* Whh_r  = (short*)p;  p += (size_t)G3 * HID * 2;      //   6.3 MB
    // total ~320 MB

    cvt_wih<<<G3, 256, 0, stream>>>(W_ih, Wih_bf);
    cvt_whh<<<G3, 256, 0, stream>>>(W_hh, Whh_r);
    cvt_x<<<BT, 256, 0, stream>>>(x, x_bf);
    hipMemsetAsync(hb0, 0, (size_t)BATCH * HID * 2, stream);

    // One big input projection over all timesteps (M = 40960, 1D swizzled)
    gemm_input<<<7680, 256, 0, stream>>>(x_bf, Wih_bf, b_ih, gx);

    // 20 fused recurrent steps (512 blocks each, XCD-swizzled)
    for (int t = 0; t < TSTEP; ++t) {
        const short* hin = (t & 1) ? hb1 : hb0;
        short* hout      = (t & 1) ? hb0 : hb1;
        gru_step<<<512, 256, 0, stream>>>(hin, Whh_r, gx, b_hh,
                                          hout, out, t, t == TSTEP - 1 ? 1 : 0);
    }
}